// Round 9
// baseline (294.880 us; speedup 1.0000x reference)
//
#include <hip/hip_runtime.h>
#include <hip/hip_bf16.h>
#include <math.h>

#define NN_C 50000
#define NE_C 800000
#define NBKT 196          // ceil(NN/256) coarse buckets (256 dst nodes each)
#define E_PER_BLK 4096
#define S1_BLOCKS 196     // ceil(NE/4096)
#define S2_CAP 8192       // bucket capacity (mean 4096, sigma ~64)
#define GEMM_RB 391       // ceil(NN/128) row-tiles
#define GEMM_BLOCKS (GEMM_RB * 3)

typedef short bf16x8 __attribute__((ext_vector_type(8)));
typedef float f32x4 __attribute__((ext_vector_type(4)));

struct U3 { unsigned int x, y, z; };   // 12 B, 4-B aligned

__device__ inline float blo(unsigned int u) { return __uint_as_float(u << 16); }
__device__ inline float bhi(unsigned int u) { return __uint_as_float(u & 0xffff0000u); }

__device__ inline unsigned short bf16rne(float f) {
    union { __hip_bfloat16 h; unsigned short u; } c;
    c.h = __float2bfloat16(f);
    return c.u;
}
__device__ inline unsigned int pk2(float a, float b) {
    return (unsigned int)bf16rne(a) | ((unsigned int)bf16rne(b) << 16);
}

__device__ inline int block_incl_scan(int v, int lane, int wid, int* ws)
{
    int x = v;
    #pragma unroll
    for (int off = 1; off < 64; off <<= 1) {
        int t = __shfl_up(x, off);
        if (lane >= off) x += t;
    }
    if (lane == 63) ws[wid] = x;
    __syncthreads();
    int woff = 0;
    #pragma unroll
    for (int w = 0; w < 4; ++w)
        if (w < wid) woff += ws[w];
    return woff + x;   // inclusive
}

// ---------------------------------------------------------------------------
// MFMA GEMM body: [M,128](bf16 or fp32->bf16) @ Wt[384,128]^T + bias -> split
// outputs agg[M][192]=k|v bf16, qs[M][192]=q|s bf16. K=128 in LDS, XOR
// swizzle (byte ^ (row&7)<<4) write-side AND read-side.
// ---------------------------------------------------------------------------
template<bool AF32>
__device__ __forceinline__ void gemm_body(
    char* lds, const void* __restrict__ Ap, const unsigned short* __restrict__ Wt,
    const float* __restrict__ bias,
    unsigned short* __restrict__ aggb, unsigned short* __restrict__ qsb,
    int M, int r0, int c0)
{
    char* sA = lds;
    char* sB = lds + 32768;
    const int tid = threadIdx.x;
    const char* Wb = (const char*)Wt + (size_t)c0 * 256;

    if (AF32) {
        const char* Asrc = (const char*)Ap;          // 512 B fp32 rows
        #pragma unroll
        for (int sct = 0; sct < 8; ++sct) {
            int o = (sct * 256 + tid) * 16;
            int r = o >> 8;
            int gr = r0 + r; if (gr > M - 1) gr = M - 1;
            const char* p = Asrc + (size_t)gr * 512 + (o & 255) * 2;
            float4 a = *reinterpret_cast<const float4*>(p);
            float4 b = *reinterpret_cast<const float4*>(p + 16);
            uint4 val;
            val.x = pk2(a.x, a.y); val.y = pk2(a.z, a.w);
            val.z = pk2(b.x, b.y); val.w = pk2(b.z, b.w);
            *reinterpret_cast<uint4*>(sA + (o ^ ((r & 7) << 4))) = val;
        }
    } else {
        const char* Asrc = (const char*)Ap;          // 256 B bf16 rows
        #pragma unroll
        for (int sct = 0; sct < 8; ++sct) {
            int o = (sct * 256 + tid) * 16;
            int r = o >> 8;
            int gr = r0 + r; if (gr > M - 1) gr = M - 1;
            uint4 val = *reinterpret_cast<const uint4*>(Asrc + (size_t)gr * 256 + (o & 255));
            *reinterpret_cast<uint4*>(sA + (o ^ ((r & 7) << 4))) = val;
        }
    }
    #pragma unroll
    for (int sct = 0; sct < 8; ++sct) {
        int o = (sct * 256 + tid) * 16;
        int r = o >> 8;
        uint4 val = *reinterpret_cast<const uint4*>(Wb + o);
        *reinterpret_cast<uint4*>(sB + (o ^ ((r & 7) << 4))) = val;
    }
    __syncthreads();

    const int lane = tid & 63, wid = tid >> 6;
    const int wm = wid >> 1, wn = wid & 1;
    const int qw = lane >> 4, c16 = lane & 15;

    f32x4 acc[4][4];
    #pragma unroll
    for (int a = 0; a < 4; ++a)
        #pragma unroll
        for (int b = 0; b < 4; ++b) acc[a][b] = (f32x4){0.f, 0.f, 0.f, 0.f};

    int aoff[4], boff[4];
    #pragma unroll
    for (int fm = 0; fm < 4; ++fm) {
        int r = wm * 64 + fm * 16 + c16;
        aoff[fm] = r * 256 + ((qw * 16) ^ ((r & 7) << 4));
    }
    #pragma unroll
    for (int fn = 0; fn < 4; ++fn) {
        int r = wn * 64 + fn * 16 + c16;
        boff[fn] = r * 256 + ((qw * 16) ^ ((r & 7) << 4));
    }

    #pragma unroll
    for (int ks = 0; ks < 4; ++ks) {
        const int kx = ks * 64;
        bf16x8 af[4], bfr[4];
        #pragma unroll
        for (int fm = 0; fm < 4; ++fm)
            af[fm] = *reinterpret_cast<const bf16x8*>(sA + (aoff[fm] ^ kx));
        #pragma unroll
        for (int fn = 0; fn < 4; ++fn)
            bfr[fn] = *reinterpret_cast<const bf16x8*>(sB + (boff[fn] ^ kx));
        #pragma unroll
        for (int fm = 0; fm < 4; ++fm)
            #pragma unroll
            for (int fn = 0; fn < 4; ++fn)
                acc[fm][fn] = __builtin_amdgcn_mfma_f32_16x16x32_bf16(
                    af[fm], bfr[fn], acc[fm][fn], 0, 0, 0);
    }

    #pragma unroll
    for (int fn = 0; fn < 4; ++fn) {
        int colbase = c0 + wn * 64 + fn * 16;
        int g = colbase / 96;
        unsigned short* obuf; int elem0;
        if (g == 0)      { obuf = qsb;  elem0 = colbase; }
        else if (g == 3) { obuf = qsb;  elem0 = colbase - 192; }
        else             { obuf = aggb; elem0 = colbase - 96; }
        float bcol = bias[colbase + c16];
        #pragma unroll
        for (int fm = 0; fm < 4; ++fm) {
            #pragma unroll
            for (int j = 0; j < 4; ++j) {
                int rg = r0 + wm * 64 + fm * 16 + qw * 4 + j;
                float o = acc[fm][fn][j] + bcol;
                float o2 = __shfl_xor(o, 1);
                if (!(lane & 1) && rg < M) {
                    *reinterpret_cast<unsigned int*>(
                        (char*)obuf + (size_t)rg * 384 + (size_t)(elem0 + c16) * 2) = pk2(o, o2);
                }
            }
        }
    }
}

template<bool AF32>
__global__ __launch_bounds__(256) void gemm_mfma(
    const void* __restrict__ Ap, const unsigned short* __restrict__ Wt,
    const float* __restrict__ bias,
    unsigned short* __restrict__ aggb, unsigned short* __restrict__ qsb, int M)
{
    __shared__ char lds[65536];
    gemm_body<AF32>(lds, Ap, Wt, bias, aggb, qsb, M, blockIdx.x * 128, blockIdx.y * 128);
}

// ---------------------------------------------------------------------------
// Setup: blocks 0-191 pack layer-1 weights, 192-383 layer-2, 384+ per-block
// histogram of dst into bucketPart[hb][NBKT] (NO atomics, no memset needed).
// ---------------------------------------------------------------------------
__global__ __launch_bounds__(256) void setup_kernel(
    const float* __restrict__ w0a, const float* __restrict__ w1a,
    const float* __restrict__ w2a, const float* __restrict__ w3a,
    const float* __restrict__ b0a, const float* __restrict__ b1a,
    const float* __restrict__ b2a, const float* __restrict__ b3a,
    const float* __restrict__ w0b, const float* __restrict__ w1b,
    const float* __restrict__ w2b, const float* __restrict__ w3b,
    const float* __restrict__ b0b, const float* __restrict__ b1b,
    const float* __restrict__ b2b, const float* __restrict__ b3b,
    const int* __restrict__ dst,
    unsigned short* __restrict__ WtA, float* __restrict__ b4a,
    unsigned short* __restrict__ WtB, float* __restrict__ b4b,
    int* __restrict__ bucketPart)
{
    __shared__ int hist[NBKT];
    const int tid = threadIdx.x;
    const int blk = blockIdx.x;
    if (blk < 384) {
        const bool L2w = blk >= 192;
        int idx = (L2w ? blk - 192 : blk) * 256 + tid;   // < 384*128
        int n = idx >> 7, k = idx & 127;
        int g = n / 96, c = n - g * 96;
        const float* w; const float* bb;
        if (!L2w) {
            w = (g == 0) ? w0a : (g == 1) ? w1a : (g == 2) ? w2a : w3a;
            bb = (g == 0) ? b0a : (g == 1) ? b1a : (g == 2) ? b2a : b3a;
            WtA[idx] = bf16rne((k < 128) ? w[(size_t)k * 96 + c] : 0.f);
            if (k == 0) b4a[n] = bb[c];
        } else {
            w = (g == 0) ? w0b : (g == 1) ? w1b : (g == 2) ? w2b : w3b;
            bb = (g == 0) ? b0b : (g == 1) ? b1b : (g == 2) ? b2b : b3b;
            WtB[idx] = bf16rne((k < 96) ? w[(size_t)k * 96 + c] : 0.f);
            if (k == 0) b4b[n] = bb[c];
        }
    } else {
        const int hb = blk - 384;
        for (int t = tid; t < NBKT; t += 256) hist[t] = 0;
        __syncthreads();
        const int e0 = hb * E_PER_BLK;
        const int ne = min(E_PER_BLK, NE_C - e0);
        for (int j = tid; j < ne; j += 256)
            atomicAdd(&hist[((unsigned)dst[e0 + j]) >> 8], 1);
        __syncthreads();
        for (int t = tid; t < NBKT; t += 256)
            bucketPart[hb * NBKT + t] = hist[t];
    }
}

// ---------------------------------------------------------------------------
// 1-block: reduce bucketPart columns -> scan -> bucketBase[NBKT+1], gCur.
// ---------------------------------------------------------------------------
__global__ __launch_bounds__(256) void scanb_kernel(
    const int* __restrict__ bucketPart, int* __restrict__ bucketBase,
    int* __restrict__ gCur)
{
    __shared__ int ws[4];
    const int tid = threadIdx.x;
    int v = 0;
    if (tid < NBKT)
        for (int b = 0; b < S1_BLOCKS; ++b) v += bucketPart[b * NBKT + tid];
    int incl = block_incl_scan(v, tid & 63, tid >> 6, ws);
    int excl = incl - v;
    if (tid < NBKT) { bucketBase[tid] = excl; gCur[tid] = excl; }
    if (tid == NBKT - 1) bucketBase[NBKT] = incl;
}

// ---------------------------------------------------------------------------
// Stage 1 body: bin this block's edges into coarse buckets (hist preloaded
// from bucketPart -> single LDS pass), write coalesced runs to bktArr.
// ---------------------------------------------------------------------------
__device__ __forceinline__ void stage1_body(
    char* ldsraw, const int* __restrict__ src, const int* __restrict__ dst,
    const int* __restrict__ bucketPart, int* __restrict__ gCur,
    unsigned int* __restrict__ bktArr, int blk)
{
    int* ip = (int*)ldsraw;
    int* hist  = ip;
    int* loff  = ip + 256;
    int* lcur  = ip + 512;
    int* gbase = ip + 768;
    int* ws    = ip + 1024;
    unsigned int* buf = (unsigned int*)(ip + 1056);
    const int tid = threadIdx.x;
    const int e0 = blk * E_PER_BLK;
    const int ne = min(E_PER_BLK, NE_C - e0);

    if (tid < NBKT) hist[tid] = bucketPart[blk * NBKT + tid];
    __syncthreads();
    {
        int v = (tid < NBKT) ? hist[tid] : 0;
        int incl = block_incl_scan(v, tid & 63, tid >> 6, ws);
        if (tid < NBKT) { loff[tid] = incl - v; lcur[tid] = incl - v; }
    }
    __syncthreads();
    for (int j = tid; j < ne; j += 256) {
        int d = dst[e0 + j], s = src[e0 + j];
        unsigned int pk = ((unsigned)d << 16) | (unsigned)s;
        int p = atomicAdd(&lcur[(unsigned)d >> 8], 1);
        buf[p] = pk;
    }
    __syncthreads();
    if (tid < NBKT) {
        int h = hist[tid];
        gbase[tid] = h ? atomicAdd(&gCur[tid], h) : 0;
    }
    __syncthreads();
    for (int j = tid; j < ne; j += 256) {
        unsigned int pk = buf[j];
        int b = pk >> 24;
        bktArr[gbase[b] + (j - loff[b])] = pk;
    }
}

// ---------------------------------------------------------------------------
// Fused: blocks [0, GEMM_BLOCKS) run layer-1 GEMM; rest run stage1 (indep.)
// ---------------------------------------------------------------------------
__global__ __launch_bounds__(256) void fused1_kernel(
    const float* __restrict__ x, const unsigned short* __restrict__ WtA,
    const float* __restrict__ b4a,
    unsigned short* __restrict__ aggb, unsigned short* __restrict__ qsb,
    const int* __restrict__ src, const int* __restrict__ dst,
    const int* __restrict__ bucketPart, int* __restrict__ gCur,
    unsigned int* __restrict__ bktArr)
{
    __shared__ char lds[65536];
    const int bx = blockIdx.x;
    if (bx < GEMM_BLOCKS) {
        int r0 = (bx % GEMM_RB) * 128;
        int c0 = (bx / GEMM_RB) * 128;
        gemm_body<true>(lds, x, WtA, b4a, aggb, qsb, NN_C, r0, c0);
    } else {
        stage1_body(lds, src, dst, bucketPart, gCur, bktArr, bx - GEMM_BLOCKS);
    }
}

// ---------------------------------------------------------------------------
// Stage 2: one block per bucket -> exact per-node CSR in LDS, coalesced
// writes of csr16 (ushort src) and row offsets.
// ---------------------------------------------------------------------------
__global__ __launch_bounds__(256) void stage2_kernel(
    const unsigned int* __restrict__ bktArr, const int* __restrict__ bucketBase,
    unsigned short* __restrict__ csr16, int* __restrict__ row)
{
    __shared__ int ncnt[256], noff[256], ncur[256];
    __shared__ unsigned short outb[S2_CAP];
    __shared__ int ws[4];
    const int tid = threadIdx.x;
    const int b = blockIdx.x;
    const int base = bucketBase[b];
    const int cnt = bucketBase[b + 1] - base;

    ncnt[tid] = 0;
    __syncthreads();
    for (int j = tid; j < cnt; j += 256)
        atomicAdd(&ncnt[(bktArr[base + j] >> 16) & 255], 1);
    __syncthreads();
    {
        int v = ncnt[tid];
        int incl = block_incl_scan(v, tid & 63, tid >> 6, ws);
        noff[tid] = incl - v; ncur[tid] = incl - v;
    }
    __syncthreads();
    for (int j = tid; j < cnt; j += 256) {
        unsigned int pk = bktArr[base + j];
        int p = atomicAdd(&ncur[(pk >> 16) & 255], 1);
        if (p < S2_CAP) outb[p] = (unsigned short)(pk & 0xFFFFu);
    }
    __syncthreads();
    for (int j = tid; j < cnt && j < S2_CAP; j += 256) csr16[base + j] = outb[j];
    const int node0 = b * 256;
    if (node0 + tid < NN_C) row[node0 + tid] = base + noff[tid];
    if (b == 0 && tid == 0) row[NN_C] = NE_C;
}

// ---------------------------------------------------------------------------
// Fused attention aggregate, quarter-wave edge mapping, 16-deep unroll.
// agg[n][192]=k|v bf16 (384 B rows), qs[n][192]=q|s bf16. Each 16-lane
// quarter owns one edge; lane l covers dims 6l..6l+5 (12 B dwordx3 gathers).
// Max-free softmax (q pre-scaled). csr16 holds ushort src ids.
// MODE 0: relu + bf16[128] zero-padded out. MODE 1: fused head -> f32[32].
// Grid must satisfy grid*4 == nnodes exactly.
// ---------------------------------------------------------------------------
template<int MODE>
__global__ __launch_bounds__(256) void aggregate_kernel(
    const unsigned short* __restrict__ aggb, const unsigned short* __restrict__ qsb,
    const int* __restrict__ row, const unsigned short* __restrict__ csr16,
    const float* __restrict__ Wd, const float* __restrict__ bd,
    void* __restrict__ outv, int nnodes)
{
    __shared__ float headL[MODE == 1 ? (96 * 32 + 32 + 4 * 96) : 1];
    const int tid  = threadIdx.x;
    const int wid  = tid >> 6;
    const int lane = tid & 63;
    const int l = lane & 15;      // dim slot: dims 6l..6l+5
    const int q = lane >> 4;      // quarter id (edge selector)
    const int n = blockIdx.x * 4 + wid;

    if constexpr (MODE == 1) {
        #pragma unroll
        for (int t = 0; t < 12; ++t) headL[t * 256 + tid] = Wd[t * 256 + tid];
        if (tid < 32) headL[3072 + tid] = bd[tid];
        __syncthreads();
    }

    const float scale = 0.10206207261596577f;   // 1/sqrt(96)
    const char* AG = (const char*)aggb;
    const char* QS = (const char*)qsb;
    const size_t qrb = (size_t)n * 384;

    U3 qd = *(const U3*)(QS + qrb + 12 * l);
    const float q0 = blo(qd.x) * scale, q1 = bhi(qd.x) * scale;
    const float q2 = blo(qd.y) * scale, q3 = bhi(qd.y) * scale;
    const float q4 = blo(qd.z) * scale, q5 = bhi(qd.z) * scale;

    const char* AGk = AG + 12 * l;         // k dims 6l..6l+5 at row+12l
    const char* AGv = AG + 192 + 12 * l;   // v dims 6l..6l+5

    float s = 0.f, a0 = 0.f, a1 = 0.f, a2 = 0.f, a3 = 0.f, a4 = 0.f, a5 = 0.f;
    const int beg = row[n], end = row[n + 1];

    auto quad = [&](int i0) {
        const unsigned int base = (unsigned int)csr16[i0 + q] * 384u;
        U3 kd = *(const U3*)(AGk + base);
        U3 vd = *(const U3*)(AGv + base);
        float p = q0 * blo(kd.x) + q1 * bhi(kd.x) + q2 * blo(kd.y)
                + q3 * bhi(kd.y) + q4 * blo(kd.z) + q5 * bhi(kd.z);
        #pragma unroll
        for (int off = 1; off < 16; off <<= 1) p += __shfl_xor(p, off);
        float e = __expf(p);
        s  += e;
        a0 += e * blo(vd.x); a1 += e * bhi(vd.x);
        a2 += e * blo(vd.y); a3 += e * bhi(vd.y);
        a4 += e * blo(vd.z); a5 += e * bhi(vd.z);
    };

    int i = beg;
    for (; i + 16 <= end; i += 16) { quad(i); quad(i + 4); quad(i + 8); quad(i + 12); }
    for (; i + 4 <= end; i += 4) quad(i);
    if (i < end) {
        const int j = i + q;
        const int jc = (j < end) ? j : (end - 1);
        const unsigned int base = (unsigned int)csr16[jc] * 384u;
        U3 kd = *(const U3*)(AGk + base);
        U3 vd = *(const U3*)(AGv + base);
        float p = q0 * blo(kd.x) + q1 * bhi(kd.x) + q2 * blo(kd.y)
                + q3 * bhi(kd.y) + q4 * blo(kd.z) + q5 * bhi(kd.z);
        #pragma unroll
        for (int off = 1; off < 16; off <<= 1) p += __shfl_xor(p, off);
        float e = (j < end) ? __expf(p) : 0.f;
        s  += e;
        a0 += e * blo(vd.x); a1 += e * bhi(vd.x);
        a2 += e * blo(vd.y); a3 += e * bhi(vd.y);
        a4 += e * blo(vd.z); a5 += e * bhi(vd.z);
    }
    // combine the four quarters (each lane keeps its dim slot l)
    #pragma unroll
    for (int off = 16; off < 64; off <<= 1) {
        s  += __shfl_xor(s, off);
        a0 += __shfl_xor(a0, off); a1 += __shfl_xor(a1, off);
        a2 += __shfl_xor(a2, off); a3 += __shfl_xor(a3, off);
        a4 += __shfl_xor(a4, off); a5 += __shfl_xor(a5, off);
    }
    const float inv = 1.0f / (s + 1e-16f);

    U3 sd = *(const U3*)(QS + qrb + 192 + 12 * l);
    float o0 = a0 * inv + blo(sd.x), o1 = a1 * inv + bhi(sd.x);
    float o2 = a2 * inv + blo(sd.y), o3 = a3 * inv + bhi(sd.y);
    float o4 = a4 * inv + blo(sd.z), o5 = a5 * inv + bhi(sd.z);

    if constexpr (MODE == 0) {
        o0 = fmaxf(o0, 0.f); o1 = fmaxf(o1, 0.f); o2 = fmaxf(o2, 0.f);
        o3 = fmaxf(o3, 0.f); o4 = fmaxf(o4, 0.f); o5 = fmaxf(o5, 0.f);
        char* O = (char*)outv;
        const size_t ob = (size_t)n * 256;
        if (q < 3) {
            float u0 = (q == 0) ? o0 : (q == 1) ? o2 : o4;
            float u1 = (q == 0) ? o1 : (q == 1) ? o3 : o5;
            *(unsigned int*)(O + ob + 12 * l + 4 * q) = pk2(u0, u1);
        } else {
            *(unsigned int*)(O + ob + 192 + 4 * l) = 0u;   // zero-pad dims 96-127
        }
    } else {
        float* oW = headL + 3104 + wid * 96;
        if (q == 0) {
            oW[6 * l + 0] = o0; oW[6 * l + 1] = o1; oW[6 * l + 2] = o2;
            oW[6 * l + 3] = o3; oW[6 * l + 4] = o4; oW[6 * l + 5] = o5;
        }
        const int c = lane & 31, h = lane >> 5;
        const int d0 = h * 48;
        float acc = 0.f;
        #pragma unroll
        for (int d = 0; d < 48; ++d)
            acc += oW[d0 + d] * headL[(d0 + d) * 32 + c];
        acc += __shfl_xor(acc, 32);
        if (lane < 32)
            ((float*)outv)[(size_t)n * 32 + c] = acc + headL[3072 + c];
    }
}

// ---------------------------------------------------------------------------
extern "C" void kernel_launch(void* const* d_in, const int* in_sizes, int n_in,
                              void* d_out, int out_size, void* d_ws, size_t ws_size,
                              hipStream_t stream)
{
    const int NN = NN_C, NE = NE_C;
    const float* x  = (const float*)d_in[0];
    const int*   ei = (const int*)d_in[1];
    const int* src = ei;
    const int* dst = ei + NE;

    const float* Wq1 = (const float*)d_in[2];  const float* bq1 = (const float*)d_in[3];
    const float* Wk1 = (const float*)d_in[4];  const float* bk1 = (const float*)d_in[5];
    const float* Wv1 = (const float*)d_in[6];  const float* bv1 = (const float*)d_in[7];
    const float* Ws1 = (const float*)d_in[8];  const float* bs1 = (const float*)d_in[9];
    const float* Wq2 = (const float*)d_in[10]; const float* bq2 = (const float*)d_in[11];
    const float* Wk2 = (const float*)d_in[12]; const float* bk2 = (const float*)d_in[13];
    const float* Wv2 = (const float*)d_in[14]; const float* bv2 = (const float*)d_in[15];
    const float* Ws2 = (const float*)d_in[16]; const float* bs2 = (const float*)d_in[17];
    const float* Wd  = (const float*)d_in[18]; const float* bd  = (const float*)d_in[19];

    char* base = (char*)d_ws;
    size_t off = 0;
    auto alloc = [&](size_t bytes) -> void* {
        void* p = base + off;
        off += (bytes + 255) & ~(size_t)255;
        return p;
    };
    unsigned short* aggb   = (unsigned short*)alloc((size_t)NN * 192 * 2);  // k|v
    unsigned short* qsb    = (unsigned short*)alloc((size_t)NN * 192 * 2);  // q|s
    unsigned short* hb16   = (unsigned short*)alloc((size_t)NN * 128 * 2);
    unsigned short* Wt4a   = (unsigned short*)alloc(384 * 128 * 2);
    unsigned short* Wt4b   = (unsigned short*)alloc(384 * 128 * 2);
    float*          b4a    = (float*)alloc(384 * 4);
    float*          b4b    = (float*)alloc(384 * 4);
    int*            bucketPart = (int*)alloc((size_t)S1_BLOCKS * NBKT * 4);
    int*            bucketBase = (int*)alloc((NBKT + 1) * 4);
    int*            gCur   = (int*)alloc(NBKT * 4);
    unsigned int*   bktArr = (unsigned int*)alloc((size_t)NE * 4);
    unsigned short* csr16  = (unsigned short*)alloc((size_t)NE * 2);
    int*            rowp   = (int*)alloc((NN + 1) * 4);

    // ---- setup: weight packing + per-block histograms (no memset needed)
    setup_kernel<<<384 + S1_BLOCKS, 256, 0, stream>>>(
        Wq1, Wk1, Wv1, Ws1, bq1, bk1, bv1, bs1,
        Wq2, Wk2, Wv2, Ws2, bq2, bk2, bv2, bs2,
        dst, Wt4a, b4a, Wt4b, b4b, bucketPart);
    scanb_kernel<<<1, 256, 0, stream>>>(bucketPart, bucketBase, gCur);

    // ---- layer-1 GEMM (fp32 x -> bf16) fused with CSR stage 1 (independent)
    fused1_kernel<<<GEMM_BLOCKS + S1_BLOCKS, 256, 0, stream>>>(
        x, Wt4a, b4a, aggb, qsb, src, dst, bucketPart, gCur, bktArr);
    stage2_kernel<<<NBKT, 256, 0, stream>>>(bktArr, bucketBase, csr16, rowp);

    const int aggGrid = NN / 4;   // exact: 50000 = 12500*4
    aggregate_kernel<0><<<aggGrid, 256, 0, stream>>>(
        aggb, qsb, rowp, csr16, nullptr, nullptr, hb16, NN);

    // ---- layer 2 (A = bf16, K zero-padded 96->128) + fused head -> d_out
    dim3 gg(GEMM_RB, 3);
    gemm_mfma<false><<<gg, 256, 0, stream>>>(hb16, Wt4b, b4b, aggb, qsb, NN);
    aggregate_kernel<1><<<aggGrid, 256, 0, stream>>>(
        aggb, qsb, rowp, csr16, Wd, bd, d_out, NN);
}

// Round 10
// 276.803 us; speedup vs baseline: 1.0653x; 1.0653x over previous
//
#include <hip/hip_runtime.h>
#include <hip/hip_bf16.h>
#include <math.h>

#define NN_C 50000
#define NE_C 800000
#define NBKT 196          // ceil(NN/256) coarse buckets (256 dst nodes each)
#define E_PER_BLK 4096
#define S1_BLOCKS 196     // ceil(NE/4096)
#define S2_CAP 8192       // bucket capacity (mean 4096, sigma ~64)
#define GEMM_RB 391       // ceil(NN/128) row-tiles
#define GEMM_BLOCKS (GEMM_RB * 3)

typedef short bf16x8 __attribute__((ext_vector_type(8)));
typedef float f32x4 __attribute__((ext_vector_type(4)));

struct U3 { unsigned int x, y, z; };   // 12 B, 4-B aligned

__device__ inline float blo(unsigned int u) { return __uint_as_float(u << 16); }
__device__ inline float bhi(unsigned int u) { return __uint_as_float(u & 0xffff0000u); }

#if __has_builtin(__builtin_amdgcn_fdot2_f32_bf16)
#define USE_DOT2 1
typedef __bf16 bf16v2 __attribute__((ext_vector_type(2)));
__device__ __forceinline__ float dot2bf(unsigned int a, unsigned int b, float c) {
    return __builtin_amdgcn_fdot2_f32_bf16(
        __builtin_bit_cast(bf16v2, a), __builtin_bit_cast(bf16v2, b), c, false);
}
#endif

__device__ inline unsigned short bf16rne(float f) {
    union { __hip_bfloat16 h; unsigned short u; } c;
    c.h = __float2bfloat16(f);
    return c.u;
}
__device__ inline unsigned int pk2(float a, float b) {
    return (unsigned int)bf16rne(a) | ((unsigned int)bf16rne(b) << 16);
}

__device__ inline int block_incl_scan(int v, int lane, int wid, int* ws)
{
    int x = v;
    #pragma unroll
    for (int off = 1; off < 64; off <<= 1) {
        int t = __shfl_up(x, off);
        if (lane >= off) x += t;
    }
    if (lane == 63) ws[wid] = x;
    __syncthreads();
    int woff = 0;
    #pragma unroll
    for (int w = 0; w < 4; ++w)
        if (w < wid) woff += ws[w];
    return woff + x;   // inclusive
}

// ---------------------------------------------------------------------------
// MFMA GEMM body: [M,128](bf16 or fp32->bf16) @ Wt[384,128]^T + bias -> split
// outputs agg[M][192]=k|v bf16, qs[M][192]=q|s bf16. K=128 in LDS, XOR
// swizzle (byte ^ (row&7)<<4) write-side AND read-side.
// ---------------------------------------------------------------------------
template<bool AF32>
__device__ __forceinline__ void gemm_body(
    char* lds, const void* __restrict__ Ap, const unsigned short* __restrict__ Wt,
    const float* __restrict__ bias,
    unsigned short* __restrict__ aggb, unsigned short* __restrict__ qsb,
    int M, int r0, int c0)
{
    char* sA = lds;
    char* sB = lds + 32768;
    const int tid = threadIdx.x;
    const char* Wb = (const char*)Wt + (size_t)c0 * 256;

    if (AF32) {
        const char* Asrc = (const char*)Ap;          // 512 B fp32 rows
        #pragma unroll
        for (int sct = 0; sct < 8; ++sct) {
            int o = (sct * 256 + tid) * 16;
            int r = o >> 8;
            int gr = r0 + r; if (gr > M - 1) gr = M - 1;
            const char* p = Asrc + (size_t)gr * 512 + (o & 255) * 2;
            float4 a = *reinterpret_cast<const float4*>(p);
            float4 b = *reinterpret_cast<const float4*>(p + 16);
            uint4 val;
            val.x = pk2(a.x, a.y); val.y = pk2(a.z, a.w);
            val.z = pk2(b.x, b.y); val.w = pk2(b.z, b.w);
            *reinterpret_cast<uint4*>(sA + (o ^ ((r & 7) << 4))) = val;
        }
    } else {
        const char* Asrc = (const char*)Ap;          // 256 B bf16 rows
        #pragma unroll
        for (int sct = 0; sct < 8; ++sct) {
            int o = (sct * 256 + tid) * 16;
            int r = o >> 8;
            int gr = r0 + r; if (gr > M - 1) gr = M - 1;
            uint4 val = *reinterpret_cast<const uint4*>(Asrc + (size_t)gr * 256 + (o & 255));
            *reinterpret_cast<uint4*>(sA + (o ^ ((r & 7) << 4))) = val;
        }
    }
    #pragma unroll
    for (int sct = 0; sct < 8; ++sct) {
        int o = (sct * 256 + tid) * 16;
        int r = o >> 8;
        uint4 val = *reinterpret_cast<const uint4*>(Wb + o);
        *reinterpret_cast<uint4*>(sB + (o ^ ((r & 7) << 4))) = val;
    }
    __syncthreads();

    const int lane = tid & 63, wid = tid >> 6;
    const int wm = wid >> 1, wn = wid & 1;
    const int qw = lane >> 4, c16 = lane & 15;

    f32x4 acc[4][4];
    #pragma unroll
    for (int a = 0; a < 4; ++a)
        #pragma unroll
        for (int b = 0; b < 4; ++b) acc[a][b] = (f32x4){0.f, 0.f, 0.f, 0.f};

    int aoff[4], boff[4];
    #pragma unroll
    for (int fm = 0; fm < 4; ++fm) {
        int r = wm * 64 + fm * 16 + c16;
        aoff[fm] = r * 256 + ((qw * 16) ^ ((r & 7) << 4));
    }
    #pragma unroll
    for (int fn = 0; fn < 4; ++fn) {
        int r = wn * 64 + fn * 16 + c16;
        boff[fn] = r * 256 + ((qw * 16) ^ ((r & 7) << 4));
    }

    #pragma unroll
    for (int ks = 0; ks < 4; ++ks) {
        const int kx = ks * 64;
        bf16x8 af[4], bfr[4];
        #pragma unroll
        for (int fm = 0; fm < 4; ++fm)
            af[fm] = *reinterpret_cast<const bf16x8*>(sA + (aoff[fm] ^ kx));
        #pragma unroll
        for (int fn = 0; fn < 4; ++fn)
            bfr[fn] = *reinterpret_cast<const bf16x8*>(sB + (boff[fn] ^ kx));
        #pragma unroll
        for (int fm = 0; fm < 4; ++fm)
            #pragma unroll
            for (int fn = 0; fn < 4; ++fn)
                acc[fm][fn] = __builtin_amdgcn_mfma_f32_16x16x32_bf16(
                    af[fm], bfr[fn], acc[fm][fn], 0, 0, 0);
    }

    #pragma unroll
    for (int fn = 0; fn < 4; ++fn) {
        int colbase = c0 + wn * 64 + fn * 16;
        int g = colbase / 96;
        unsigned short* obuf; int elem0;
        if (g == 0)      { obuf = qsb;  elem0 = colbase; }
        else if (g == 3) { obuf = qsb;  elem0 = colbase - 192; }
        else             { obuf = aggb; elem0 = colbase - 96; }
        float bcol = bias[colbase + c16];
        #pragma unroll
        for (int fm = 0; fm < 4; ++fm) {
            #pragma unroll
            for (int j = 0; j < 4; ++j) {
                int rg = r0 + wm * 64 + fm * 16 + qw * 4 + j;
                float o = acc[fm][fn][j] + bcol;
                float o2 = __shfl_xor(o, 1);
                if (!(lane & 1) && rg < M) {
                    *reinterpret_cast<unsigned int*>(
                        (char*)obuf + (size_t)rg * 384 + (size_t)(elem0 + c16) * 2) = pk2(o, o2);
                }
            }
        }
    }
}

template<bool AF32>
__global__ __launch_bounds__(256) void gemm_mfma(
    const void* __restrict__ Ap, const unsigned short* __restrict__ Wt,
    const float* __restrict__ bias,
    unsigned short* __restrict__ aggb, unsigned short* __restrict__ qsb, int M)
{
    __shared__ char lds[65536];
    gemm_body<AF32>(lds, Ap, Wt, bias, aggb, qsb, M, blockIdx.x * 128, blockIdx.y * 128);
}

// ---------------------------------------------------------------------------
// Setup: blocks 0-191 pack layer-1 weights, 192-383 layer-2, 384+ per-block
// histogram of dst into bucketPart[hb][NBKT] (NO atomics, no memset needed).
// ---------------------------------------------------------------------------
__global__ __launch_bounds__(256) void setup_kernel(
    const float* __restrict__ w0a, const float* __restrict__ w1a,
    const float* __restrict__ w2a, const float* __restrict__ w3a,
    const float* __restrict__ b0a, const float* __restrict__ b1a,
    const float* __restrict__ b2a, const float* __restrict__ b3a,
    const float* __restrict__ w0b, const float* __restrict__ w1b,
    const float* __restrict__ w2b, const float* __restrict__ w3b,
    const float* __restrict__ b0b, const float* __restrict__ b1b,
    const float* __restrict__ b2b, const float* __restrict__ b3b,
    const int* __restrict__ dst,
    unsigned short* __restrict__ WtA, float* __restrict__ b4a,
    unsigned short* __restrict__ WtB, float* __restrict__ b4b,
    int* __restrict__ bucketPart)
{
    __shared__ int hist[NBKT];
    const int tid = threadIdx.x;
    const int blk = blockIdx.x;
    if (blk < 384) {
        const bool L2w = blk >= 192;
        int idx = (L2w ? blk - 192 : blk) * 256 + tid;   // < 384*128
        int n = idx >> 7, k = idx & 127;
        int g = n / 96, c = n - g * 96;
        const float* w; const float* bb;
        if (!L2w) {
            w = (g == 0) ? w0a : (g == 1) ? w1a : (g == 2) ? w2a : w3a;
            bb = (g == 0) ? b0a : (g == 1) ? b1a : (g == 2) ? b2a : b3a;
            WtA[idx] = bf16rne((k < 128) ? w[(size_t)k * 96 + c] : 0.f);
            if (k == 0) b4a[n] = bb[c];
        } else {
            w = (g == 0) ? w0b : (g == 1) ? w1b : (g == 2) ? w2b : w3b;
            bb = (g == 0) ? b0b : (g == 1) ? b1b : (g == 2) ? b2b : b3b;
            WtB[idx] = bf16rne((k < 96) ? w[(size_t)k * 96 + c] : 0.f);
            if (k == 0) b4b[n] = bb[c];
        }
    } else {
        const int hb = blk - 384;
        for (int t = tid; t < NBKT; t += 256) hist[t] = 0;
        __syncthreads();
        const int e0 = hb * E_PER_BLK;
        const int ne = min(E_PER_BLK, NE_C - e0);
        for (int j = tid; j < ne; j += 256)
            atomicAdd(&hist[((unsigned)dst[e0 + j]) >> 8], 1);
        __syncthreads();
        for (int t = tid; t < NBKT; t += 256)
            bucketPart[hb * NBKT + t] = hist[t];
    }
}

// ---------------------------------------------------------------------------
// 1-block: reduce bucketPart columns -> scan -> bucketBase[NBKT+1], gCur.
// ---------------------------------------------------------------------------
__global__ __launch_bounds__(256) void scanb_kernel(
    const int* __restrict__ bucketPart, int* __restrict__ bucketBase,
    int* __restrict__ gCur)
{
    __shared__ int ws[4];
    const int tid = threadIdx.x;
    int v = 0;
    if (tid < NBKT)
        for (int b = 0; b < S1_BLOCKS; ++b) v += bucketPart[b * NBKT + tid];
    int incl = block_incl_scan(v, tid & 63, tid >> 6, ws);
    int excl = incl - v;
    if (tid < NBKT) { bucketBase[tid] = excl; gCur[tid] = excl; }
    if (tid == NBKT - 1) bucketBase[NBKT] = incl;
}

// ---------------------------------------------------------------------------
// Stage 1 body: bin this block's edges into coarse buckets (hist preloaded
// from bucketPart -> single LDS pass), write coalesced runs to bktArr.
// ---------------------------------------------------------------------------
__device__ __forceinline__ void stage1_body(
    char* ldsraw, const int* __restrict__ src, const int* __restrict__ dst,
    const int* __restrict__ bucketPart, int* __restrict__ gCur,
    unsigned int* __restrict__ bktArr, int blk)
{
    int* ip = (int*)ldsraw;
    int* hist  = ip;
    int* loff  = ip + 256;
    int* lcur  = ip + 512;
    int* gbase = ip + 768;
    int* ws    = ip + 1024;
    unsigned int* buf = (unsigned int*)(ip + 1056);
    const int tid = threadIdx.x;
    const int e0 = blk * E_PER_BLK;
    const int ne = min(E_PER_BLK, NE_C - e0);

    if (tid < NBKT) hist[tid] = bucketPart[blk * NBKT + tid];
    __syncthreads();
    {
        int v = (tid < NBKT) ? hist[tid] : 0;
        int incl = block_incl_scan(v, tid & 63, tid >> 6, ws);
        if (tid < NBKT) { loff[tid] = incl - v; lcur[tid] = incl - v; }
    }
    __syncthreads();
    for (int j = tid; j < ne; j += 256) {
        int d = dst[e0 + j], s = src[e0 + j];
        unsigned int pk = ((unsigned)d << 16) | (unsigned)s;
        int p = atomicAdd(&lcur[(unsigned)d >> 8], 1);
        buf[p] = pk;
    }
    __syncthreads();
    if (tid < NBKT) {
        int h = hist[tid];
        gbase[tid] = h ? atomicAdd(&gCur[tid], h) : 0;
    }
    __syncthreads();
    for (int j = tid; j < ne; j += 256) {
        unsigned int pk = buf[j];
        int b = pk >> 24;
        bktArr[gbase[b] + (j - loff[b])] = pk;
    }
}

// ---------------------------------------------------------------------------
// Fused: blocks [0, GEMM_BLOCKS) run layer-1 GEMM; rest run stage1 (indep.)
// ---------------------------------------------------------------------------
__global__ __launch_bounds__(256) void fused1_kernel(
    const float* __restrict__ x, const unsigned short* __restrict__ WtA,
    const float* __restrict__ b4a,
    unsigned short* __restrict__ aggb, unsigned short* __restrict__ qsb,
    const int* __restrict__ src, const int* __restrict__ dst,
    const int* __restrict__ bucketPart, int* __restrict__ gCur,
    unsigned int* __restrict__ bktArr)
{
    __shared__ char lds[65536];
    const int bx = blockIdx.x;
    if (bx < GEMM_BLOCKS) {
        int r0 = (bx % GEMM_RB) * 128;
        int c0 = (bx / GEMM_RB) * 128;
        gemm_body<true>(lds, x, WtA, b4a, aggb, qsb, NN_C, r0, c0);
    } else {
        stage1_body(lds, src, dst, bucketPart, gCur, bktArr, bx - GEMM_BLOCKS);
    }
}

// ---------------------------------------------------------------------------
// Stage 2: one block per bucket -> exact per-node CSR in LDS, coalesced
// writes of csr16 (ushort src) and row offsets.
// ---------------------------------------------------------------------------
__global__ __launch_bounds__(256) void stage2_kernel(
    const unsigned int* __restrict__ bktArr, const int* __restrict__ bucketBase,
    unsigned short* __restrict__ csr16, int* __restrict__ row)
{
    __shared__ int ncnt[256], noff[256], ncur[256];
    __shared__ unsigned short outb[S2_CAP];
    __shared__ int ws[4];
    const int tid = threadIdx.x;
    const int b = blockIdx.x;
    const int base = bucketBase[b];
    const int cnt = bucketBase[b + 1] - base;

    ncnt[tid] = 0;
    __syncthreads();
    for (int j = tid; j < cnt; j += 256)
        atomicAdd(&ncnt[(bktArr[base + j] >> 16) & 255], 1);
    __syncthreads();
    {
        int v = ncnt[tid];
        int incl = block_incl_scan(v, tid & 63, tid >> 6, ws);
        noff[tid] = incl - v; ncur[tid] = incl - v;
    }
    __syncthreads();
    for (int j = tid; j < cnt; j += 256) {
        unsigned int pk = bktArr[base + j];
        int p = atomicAdd(&ncur[(pk >> 16) & 255], 1);
        if (p < S2_CAP) outb[p] = (unsigned short)(pk & 0xFFFFu);
    }
    __syncthreads();
    for (int j = tid; j < cnt && j < S2_CAP; j += 256) csr16[base + j] = outb[j];
    const int node0 = b * 256;
    if (node0 + tid < NN_C) row[node0 + tid] = base + noff[tid];
    if (b == 0 && tid == 0) row[NN_C] = NE_C;
}

// ---------------------------------------------------------------------------
// Fused attention aggregate, quarter-wave edge mapping, 8-deep unroll
// (2 quads in flight — VGPR 32 / occupancy-sweet-spot per R8/R9 A/B).
// agg[n][192]=k|v bf16 (384 B rows), qs[n][192]=q|s bf16. Each 16-lane
// quarter owns one edge; lane l covers dims 6l..6l+5 (12 B dwordx3 gathers).
// QK dot via v_dot2_f32_bf16 when available (packed q, 3 instr vs 12).
// Max-free softmax. csr16 holds ushort src ids.
// MODE 0: relu + bf16[128] zero-padded out. MODE 1: fused head -> f32[32].
// Grid must satisfy grid*4 == nnodes exactly.
// ---------------------------------------------------------------------------
template<int MODE>
__global__ __launch_bounds__(256) void aggregate_kernel(
    const unsigned short* __restrict__ aggb, const unsigned short* __restrict__ qsb,
    const int* __restrict__ row, const unsigned short* __restrict__ csr16,
    const float* __restrict__ Wd, const float* __restrict__ bd,
    void* __restrict__ outv, int nnodes)
{
    __shared__ float headL[MODE == 1 ? (96 * 32 + 32 + 4 * 96) : 1];
    const int tid  = threadIdx.x;
    const int wid  = tid >> 6;
    const int lane = tid & 63;
    const int l = lane & 15;      // dim slot: dims 6l..6l+5
    const int q = lane >> 4;      // quarter id (edge selector)
    const int n = blockIdx.x * 4 + wid;

    if constexpr (MODE == 1) {
        #pragma unroll
        for (int t = 0; t < 12; ++t) headL[t * 256 + tid] = Wd[t * 256 + tid];
        if (tid < 32) headL[3072 + tid] = bd[tid];
        __syncthreads();
    }

    const float scale = 0.10206207261596577f;   // 1/sqrt(96)
    const char* AG = (const char*)aggb;
    const char* QS = (const char*)qsb;
    const size_t qrb = (size_t)n * 384;

    U3 qd = *(const U3*)(QS + qrb + 12 * l);
#if !defined(USE_DOT2)
    const float q0 = blo(qd.x) * scale, q1 = bhi(qd.x) * scale;
    const float q2 = blo(qd.y) * scale, q3 = bhi(qd.y) * scale;
    const float q4 = blo(qd.z) * scale, q5 = bhi(qd.z) * scale;
#endif

    const char* AGk = AG + 12 * l;         // k dims 6l..6l+5 at row+12l
    const char* AGv = AG + 192 + 12 * l;   // v dims 6l..6l+5

    float s = 0.f, a0 = 0.f, a1 = 0.f, a2 = 0.f, a3 = 0.f, a4 = 0.f, a5 = 0.f;
    const int beg = row[n], end = row[n + 1];

    auto quad = [&](int i0) {
        const unsigned int base = (unsigned int)csr16[i0 + q] * 384u;
        U3 kd = *(const U3*)(AGk + base);
        U3 vd = *(const U3*)(AGv + base);
#if defined(USE_DOT2)
        float p = dot2bf(qd.z, kd.z, dot2bf(qd.y, kd.y, dot2bf(qd.x, kd.x, 0.f)));
        #pragma unroll
        for (int off = 1; off < 16; off <<= 1) p += __shfl_xor(p, off);
        float e = __expf(p * scale);
#else
        float p = q0 * blo(kd.x) + q1 * bhi(kd.x) + q2 * blo(kd.y)
                + q3 * bhi(kd.y) + q4 * blo(kd.z) + q5 * bhi(kd.z);
        #pragma unroll
        for (int off = 1; off < 16; off <<= 1) p += __shfl_xor(p, off);
        float e = __expf(p);
#endif
        s  += e;
        a0 += e * blo(vd.x); a1 += e * bhi(vd.x);
        a2 += e * blo(vd.y); a3 += e * bhi(vd.y);
        a4 += e * blo(vd.z); a5 += e * bhi(vd.z);
    };

    int i = beg;
    for (; i + 8 <= end; i += 8) { quad(i); quad(i + 4); }
    for (; i + 4 <= end; i += 4) quad(i);
    if (i < end) {
        const int j = i + q;
        const int jc = (j < end) ? j : (end - 1);
        const unsigned int base = (unsigned int)csr16[jc] * 384u;
        U3 kd = *(const U3*)(AGk + base);
        U3 vd = *(const U3*)(AGv + base);
#if defined(USE_DOT2)
        float p = dot2bf(qd.z, kd.z, dot2bf(qd.y, kd.y, dot2bf(qd.x, kd.x, 0.f)));
        #pragma unroll
        for (int off = 1; off < 16; off <<= 1) p += __shfl_xor(p, off);
        float e = (j < end) ? __expf(p * scale) : 0.f;
#else
        float p = q0 * blo(kd.x) + q1 * bhi(kd.x) + q2 * blo(kd.y)
                + q3 * bhi(kd.y) + q4 * blo(kd.z) + q5 * bhi(kd.z);
        #pragma unroll
        for (int off = 1; off < 16; off <<= 1) p += __shfl_xor(p, off);
        float e = (j < end) ? __expf(p) : 0.f;
#endif
        s  += e;
        a0 += e * blo(vd.x); a1 += e * bhi(vd.x);
        a2 += e * blo(vd.y); a3 += e * bhi(vd.y);
        a4 += e * blo(vd.z); a5 += e * bhi(vd.z);
    }
    // combine the four quarters (each lane keeps its dim slot l)
    #pragma unroll
    for (int off = 16; off < 64; off <<= 1) {
        s  += __shfl_xor(s, off);
        a0 += __shfl_xor(a0, off); a1 += __shfl_xor(a1, off);
        a2 += __shfl_xor(a2, off); a3 += __shfl_xor(a3, off);
        a4 += __shfl_xor(a4, off); a5 += __shfl_xor(a5, off);
    }
    const float inv = 1.0f / (s + 1e-16f);

    U3 sd = *(const U3*)(QS + qrb + 192 + 12 * l);
    float o0 = a0 * inv + blo(sd.x), o1 = a1 * inv + bhi(sd.x);
    float o2 = a2 * inv + blo(sd.y), o3 = a3 * inv + bhi(sd.y);
    float o4 = a4 * inv + blo(sd.z), o5 = a5 * inv + bhi(sd.z);

    if constexpr (MODE == 0) {
        o0 = fmaxf(o0, 0.f); o1 = fmaxf(o1, 0.f); o2 = fmaxf(o2, 0.f);
        o3 = fmaxf(o3, 0.f); o4 = fmaxf(o4, 0.f); o5 = fmaxf(o5, 0.f);
        char* O = (char*)outv;
        const size_t ob = (size_t)n * 256;
        if (q < 3) {
            float u0 = (q == 0) ? o0 : (q == 1) ? o2 : o4;
            float u1 = (q == 0) ? o1 : (q == 1) ? o3 : o5;
            *(unsigned int*)(O + ob + 12 * l + 4 * q) = pk2(u0, u1);
        } else {
            *(unsigned int*)(O + ob + 192 + 4 * l) = 0u;   // zero-pad dims 96-127
        }
    } else {
        float* oW = headL + 3104 + wid * 96;
        if (q == 0) {
            oW[6 * l + 0] = o0; oW[6 * l + 1] = o1; oW[6 * l + 2] = o2;
            oW[6 * l + 3] = o3; oW[6 * l + 4] = o4; oW[6 * l + 5] = o5;
        }
        const int c = lane & 31, h = lane >> 5;
        const int d0 = h * 48;
        float acc = 0.f;
        #pragma unroll
        for (int d = 0; d < 48; ++d)
            acc += oW[d0 + d] * headL[(d0 + d) * 32 + c];
        acc += __shfl_xor(acc, 32);
        if (lane < 32)
            ((float*)outv)[(size_t)n * 32 + c] = acc + headL[3072 + c];
    }
}

// ---------------------------------------------------------------------------
extern "C" void kernel_launch(void* const* d_in, const int* in_sizes, int n_in,
                              void* d_out, int out_size, void* d_ws, size_t ws_size,
                              hipStream_t stream)
{
    const int NN = NN_C, NE = NE_C;
    const float* x  = (const float*)d_in[0];
    const int*   ei = (const int*)d_in[1];
    const int* src = ei;
    const int* dst = ei + NE;

    const float* Wq1 = (const float*)d_in[2];  const float* bq1 = (const float*)d_in[3];
    const float* Wk1 = (const float*)d_in[4];  const float* bk1 = (const float*)d_in[5];
    const float* Wv1 = (const float*)d_in[6];  const float* bv1 = (const float*)d_in[7];
    const float* Ws1 = (const float*)d_in[8];  const float* bs1 = (const float*)d_in[9];
    const float* Wq2 = (const float*)d_in[10]; const float* bq2 = (const float*)d_in[11];
    const float* Wk2 = (const float*)d_in[12]; const float* bk2 = (const float*)d_in[13];
    const float* Wv2 = (const float*)d_in[14]; const float* bv2 = (const float*)d_in[15];
    const float* Ws2 = (const float*)d_in[16]; const float* bs2 = (const float*)d_in[17];
    const float* Wd  = (const float*)d_in[18]; const float* bd  = (const float*)d_in[19];

    char* base = (char*)d_ws;
    size_t off = 0;
    auto alloc = [&](size_t bytes) -> void* {
        void* p = base + off;
        off += (bytes + 255) & ~(size_t)255;
        return p;
    };
    unsigned short* aggb   = (unsigned short*)alloc((size_t)NN * 192 * 2);  // k|v
    unsigned short* qsb    = (unsigned short*)alloc((size_t)NN * 192 * 2);  // q|s
    unsigned short* hb16   = (unsigned short*)alloc((size_t)NN * 128 * 2);
    unsigned short* Wt4a   = (unsigned short*)alloc(384 * 128 * 2);
    unsigned short* Wt4b   = (unsigned short*)alloc(384 * 128 * 2);
    float*          b4a    = (float*)alloc(384 * 4);
    float*          b4b    = (float*)alloc(384 * 4);
    int*            bucketPart = (int*)alloc((size_t)S1_BLOCKS * NBKT * 4);
    int*            bucketBase = (int*)alloc((NBKT + 1) * 4);
    int*            gCur   = (int*)alloc(NBKT * 4);
    unsigned int*   bktArr = (unsigned int*)alloc((size_t)NE * 4);
    unsigned short* csr16  = (unsigned short*)alloc((size_t)NE * 2);
    int*            rowp   = (int*)alloc((NN + 1) * 4);

    // ---- setup: weight packing + per-block histograms (no memset needed)
    setup_kernel<<<384 + S1_BLOCKS, 256, 0, stream>>>(
        Wq1, Wk1, Wv1, Ws1, bq1, bk1, bv1, bs1,
        Wq2, Wk2, Wv2, Ws2, bq2, bk2, bv2, bs2,
        dst, Wt4a, b4a, Wt4b, b4b, bucketPart);
    scanb_kernel<<<1, 256, 0, stream>>>(bucketPart, bucketBase, gCur);

    // ---- layer-1 GEMM (fp32 x -> bf16) fused with CSR stage 1 (independent)
    fused1_kernel<<<GEMM_BLOCKS + S1_BLOCKS, 256, 0, stream>>>(
        x, Wt4a, b4a, aggb, qsb, src, dst, bucketPart, gCur, bktArr);
    stage2_kernel<<<NBKT, 256, 0, stream>>>(bktArr, bucketBase, csr16, rowp);

    const int aggGrid = NN / 4;   // exact: 50000 = 12500*4
    aggregate_kernel<0><<<aggGrid, 256, 0, stream>>>(
        aggb, qsb, rowp, csr16, nullptr, nullptr, hb16, NN);

    // ---- layer 2 (A = bf16, K zero-padded 96->128) + fused head -> d_out
    dim3 gg(GEMM_RB, 3);
    gemm_mfma<false><<<gg, 256, 0, stream>>>(hb16, Wt4b, b4b, aggb, qsb, NN);
    aggregate_kernel<1><<<aggGrid, 256, 0, stream>>>(
        aggb, qsb, rowp, csr16, Wd, bd, d_out, NN);
}